// Round 7
// baseline (1586.633 us; speedup 1.0000x reference)
//
#include <hip/hip_runtime.h>
#include <stdint.h>
#include <stddef.h>

#define Bn    16
#define Nn    10000
#define En    320000
#define CIN   32
#define COUTn 64
#define CCn   96
#define WROWU 768           // uints per full node row (16 batches * 96ch / 2)
#define RHU   512           // uints per rh-only node row (16 * 64 / 2)
#define MROWS 160000        // Nn * Bn

typedef __attribute__((ext_vector_type(8))) short short8;   // 8 bf16 = 4 VGPRs
typedef __attribute__((ext_vector_type(4))) float f32x4;

// ---------------- bf16 helpers ----------------
__device__ __forceinline__ float bflo(unsigned int p) { return __uint_as_float(p << 16); }
__device__ __forceinline__ float bfhi(unsigned int p) { return __uint_as_float(p & 0xffff0000u); }
__device__ __forceinline__ float bf2f(unsigned short u) { return __uint_as_float(((unsigned int)u) << 16); }
__device__ __forceinline__ unsigned int f2bfbits(float f) {
  unsigned int x = __float_as_uint(f);
  return (x + 0x7fffu + ((x >> 16) & 1u)) >> 16;
}
__device__ __forceinline__ unsigned int pack2(float lo, float hi) {
  return f2bfbits(lo) | (f2bfbits(hi) << 16);
}

// ---------------- edge_index dtype detection ----------------
__global__ void detect_idx(const int* __restrict__ idx, int* __restrict__ flag) {
  if (threadIdx.x == 0 && blockIdx.x == 0) {
    int is64 = 1;
    for (int i = 1; i < 128; i += 2) {
      if (idx[i] != 0) { is64 = 0; break; }
    }
    flag[0] = is64;
  }
}

__device__ __forceinline__ int gidx(const int* __restrict__ p, int i, int is64) {
  return is64 ? p[2 * (long long)i] : p[i];
}

// ---------------- degree + CSR row counts ----------------
__global__ void deg_cnt_kernel(const int* __restrict__ idx, const float* __restrict__ w,
                               float* __restrict__ deg_f, float* __restrict__ deg_b,
                               int* __restrict__ cnt_f, int* __restrict__ cnt_b,
                               const int* __restrict__ flag) {
  int e = blockIdx.x * 256 + threadIdx.x;
  int is64 = flag[0];
  if (e < En) {
    int s = gidx(idx, e, is64);
    int d = gidx(idx, En + e, is64);
    float we = w[e];
    atomicAdd(&deg_f[s], we);
    atomicAdd(&deg_b[d], we);
    atomicAdd(&cnt_f[d], 1);
    atomicAdd(&cnt_b[s], 1);
  }
}

// ---------------- exclusive scan ----------------
__global__ void exscan_two(const int* __restrict__ cnt_f, const int* __restrict__ cnt_b,
                           int* __restrict__ rp_f, int* __restrict__ rp_b,
                           int* __restrict__ cur_f, int* __restrict__ cur_b, int n) {
  const int* cnt = (blockIdx.x == 0) ? cnt_f : cnt_b;
  int* rp  = (blockIdx.x == 0) ? rp_f  : rp_b;
  int* cur = (blockIdx.x == 0) ? cur_f : cur_b;
  __shared__ int sh[256];
  int t = threadIdx.x;
  int running = 0;
  for (int base = 0; base < n; base += 256) {
    int v = (base + t < n) ? cnt[base + t] : 0;
    sh[t] = v;
    __syncthreads();
    for (int off = 1; off < 256; off <<= 1) {
      int x = (t >= off) ? sh[t - off] : 0;
      __syncthreads();
      sh[t] += x;
      __syncthreads();
    }
    int excl = sh[t] - v;
    if (base + t < n) { rp[base + t] = running + excl; cur[base + t] = running + excl; }
    int total = sh[255];
    __syncthreads();
    running += total;
  }
  if (t == 0) rp[n] = running;
}

// ---------------- CSR fill (compressed edges: col<<16 | bf16 weight) ----------------
__global__ void fill_csr(const int* __restrict__ idx, const float* __restrict__ w,
                         const float* __restrict__ deg_f, const float* __restrict__ deg_b,
                         int* __restrict__ cur_f, int* __restrict__ cur_b,
                         unsigned int* __restrict__ ecf, unsigned int* __restrict__ ecb,
                         const int* __restrict__ flag) {
  int e = blockIdx.x * 256 + threadIdx.x;
  int is64 = flag[0];
  if (e < En) {
    int s = gidx(idx, e, is64);
    int d = gidx(idx, En + e, is64);
    float we = w[e];
    int pf = atomicAdd(&cur_f[d], 1);   // forward rows=dst, col=src, w=we/deg_f[src]
    ecf[pf] = ((unsigned int)s << 16) | f2bfbits(we / deg_f[s]);
    int pb = atomicAdd(&cur_b[s], 1);   // backward rows=src, col=dst, w=we/deg_b[dst]
    ecb[pb] = ((unsigned int)d << 16) | f2bfbits(we / deg_b[d]);
  }
}

// ---------------- weight prep: transposed bf16, W0 folded (W0-W3-W4) ----------------
__global__ void build_wt(const float* __restrict__ ru_p, const float* __restrict__ c_p,
                         unsigned short* __restrict__ Wt1, unsigned short* __restrict__ Wt2) {
  int i = blockIdx.x * 256 + threadIdx.x;
  if (i < 128 * 480) {
    int n = i / 480, k = i % 480;
    int t = k / 96, kk = k % 96;
    float v;
    if (t == 0) v = ru_p[(kk * 5 + 0) * 128 + n] - ru_p[(kk * 5 + 3) * 128 + n] - ru_p[(kk * 5 + 4) * 128 + n];
    else        v = ru_p[(kk * 5 + t) * 128 + n];
    Wt1[i] = (unsigned short)f2bfbits(v);
  }
  if (i < 64 * 480) {
    int n = i / 480, k = i % 480;
    int t = k / 96, kk = k % 96;
    float v;
    if (t == 0) v = c_p[(kk * 5 + 0) * 64 + n] - c_p[(kk * 5 + 3) * 64 + n] - c_p[(kk * 5 + 4) * 64 + n];
    else        v = c_p[(kk * 5 + t) * 64 + n];
    Wt2[i] = (unsigned short)f2bfbits(v);
  }
}

// ---------------- X0 builder ----------------
__global__ void build_x0_ru(const float* __restrict__ x, const float* __restrict__ h,
                            unsigned int* __restrict__ X0) {
  long long p = (long long)blockIdx.x * 256 + threadIdx.x;
  int node = (int)(p / WROWU);
  int rem = (int)(p % WROWU);
  int b = rem / 48;
  int ci = (rem % 48) * 2;
  float lo, hi;
  if (ci < CIN) {
    const float* s = x + ((size_t)b * Nn + node) * CIN + ci;
    lo = s[0]; hi = s[1];
  } else {
    const float* s = h + ((size_t)b * Nn + node) * COUTn + (ci - CIN);
    lo = s[0]; hi = s[1];
  }
  X0[p] = pack2(lo, hi);
}

// ---------------- XCD-pinned propagate ----------------
// Grid: Nn * NCHUNK, idx = row*NCHUNK + c. With NCHUNK % 8 == 0 and round-robin
// workgroup->XCD dispatch, chunk c lands on XCD c%8 -> per-XCD gather working set
// = Nn * CSZ * 4 * (NCHUNK/8) bytes (3.84 MB wide, 2.5 MB rh) -> L2-resident.
// Block: 4 edge-slots (one wave each) x 64 lanes; lane < CSZ owns one uint of the chunk.
template<int CSZ, int NCHUNK>
__device__ __forceinline__ void prop8_body(const unsigned int* __restrict__ in,
                                           unsigned int* __restrict__ out,
                                           const int* __restrict__ rowptr,
                                           const unsigned int* __restrict__ ec,
                                           float alpha, int rowU, int row, int coff,
                                           unsigned int* sec, float (*sA)[CSZ], float (*sB)[CSZ]) {
  int slot = threadIdx.x >> 6;
  int lane = threadIdx.x & 63;
  float alo = 0.f, ahi = 0.f;
  int jb = rowptr[row], je = rowptr[row + 1];
  for (int base = jb; base < je; base += 256) {
    int m = je - base; if (m > 256) m = 256;
    __syncthreads();
    if (threadIdx.x < m) sec[threadIdx.x] = ec[base + threadIdx.x];
    __syncthreads();
    if (lane < CSZ) {
      int j = slot;
      for (; j + 4 < m; j += 8) {
        unsigned int e0 = sec[j], e1 = sec[j + 4];
        unsigned int p0 = in[(size_t)(e0 >> 16) * rowU + coff + lane];
        unsigned int p1 = in[(size_t)(e1 >> 16) * rowU + coff + lane];
        float w0 = bflo(e0), w1 = bflo(e1);
        alo += w0 * bflo(p0); ahi += w0 * bfhi(p0);
        alo += w1 * bflo(p1); ahi += w1 * bfhi(p1);
      }
      for (; j < m; j += 4) {
        unsigned int e0 = sec[j];
        unsigned int p0 = in[(size_t)(e0 >> 16) * rowU + coff + lane];
        float w0 = bflo(e0);
        alo += w0 * bflo(p0); ahi += w0 * bfhi(p0);
      }
    }
  }
  if (lane < CSZ) { sA[slot][lane] = alo; sB[slot][lane] = ahi; }
  __syncthreads();
  if (slot == 0 && lane < CSZ) {
    float a = sA[0][lane] + sA[1][lane] + sA[2][lane] + sA[3][lane];
    float b = sB[0][lane] + sB[1][lane] + sB[2][lane] + sB[3][lane];
    __builtin_nontemporal_store(pack2(alpha * a, alpha * b),
                                &out[(size_t)row * rowU + coff + lane]);
  }
}

template<int CSZ, int NCHUNK>
__launch_bounds__(256)
__global__ void prop8_single(const unsigned int* __restrict__ in, unsigned int* __restrict__ out,
                             const int* __restrict__ rowptr, const unsigned int* __restrict__ ec,
                             float alpha, int rowU) {
  __shared__ unsigned int sec[256];
  __shared__ float sA[4][CSZ], sB[4][CSZ];
  int row = blockIdx.x / NCHUNK;
  int c = blockIdx.x % NCHUNK;
  prop8_body<CSZ, NCHUNK>(in, out, rowptr, ec, alpha, rowU, row, c * CSZ, sec, sA, sB);
}

template<int CSZ, int NCHUNK>
__launch_bounds__(256)
__global__ void prop8_dual(const unsigned int* __restrict__ in,
                           unsigned int* __restrict__ outF, unsigned int* __restrict__ outB,
                           const int* __restrict__ rp_f, const unsigned int* __restrict__ ecf,
                           const int* __restrict__ rp_b, const unsigned int* __restrict__ ecb,
                           int rowU) {
  __shared__ unsigned int sec[256];
  __shared__ float sA[4][CSZ], sB[4][CSZ];
  int row = blockIdx.x / NCHUNK;
  int c = blockIdx.x % NCHUNK;
  int coff = c * CSZ;
  prop8_body<CSZ, NCHUNK>(in, outF, rp_f, ecf, 1.f, rowU, row, coff, sec, sA, sB);
  __syncthreads();
  prop8_body<CSZ, NCHUNK>(in, outB, rp_b, ecb, 1.f, rowU, row, coff, sec, sA, sB);
}

// ---------------- MFMA multi-term GEMM ----------------
// C[128 x NT] per block; 4 waves, each 32 x NT. K = nterms*96.
// Weight columns for loop term t: (t0 + t)*96.
// MODE 0: conv1 epilogue: v=sigmoid(bias+acc); col<64 -> rh0=v*h (bf16); else U=v (bf16)
// MODE 1: outp = bias + acc (f32, batch-major)
// MODE 2: cp = outp + acc; c=tanh(tanh(cp)); u from U_in; outp = u*h + (1-u)*c
struct Msrc {
  const uint4* xs[5];
  const uint4* rh[5];
};

template<int NT, int MODE>
__launch_bounds__(256)
__global__ void gemm_mfma(Msrc g, int nterms, int t0,
                          const unsigned short* __restrict__ Wt,
                          const float* __restrict__ bias,
                          float* __restrict__ outp,
                          unsigned short* __restrict__ rh0_s,
                          unsigned short* __restrict__ U_out,
                          const unsigned short* __restrict__ U_in,
                          const float* __restrict__ hglob) {
  constexpr int NJ = NT / 16;
  __shared__ __align__(16) unsigned short As[128][104];   // 13 x 16B per row (odd -> conflict-free)
  __shared__ __align__(16) unsigned short Bs[NT][104];

  int m0 = blockIdx.x * 128;
  int tid = threadIdx.x;
  int wave = tid >> 6;
  int lane = tid & 63;
  int quad = lane >> 4;
  int lm = lane & 15;
  int wm = wave * 32;
  int nodeBase = m0 >> 4;

  f32x4 acc[2][NJ];
  #pragma unroll
  for (int i = 0; i < 2; ++i)
    #pragma unroll
    for (int j = 0; j < NJ; ++j) acc[i][j] = (f32x4){0.f, 0.f, 0.f, 0.f};

  for (int t = 0; t < nterms; ++t) {
    const uint4* xs4 = g.xs[t];
    const uint4* rh4 = g.rh[t];
    if (rh4 == nullptr) {
      const uint4* src = xs4 + (size_t)m0 * 12;
      #pragma unroll
      for (int it = 0; it < 6; ++it) {
        int q = tid + it * 256;
        uint4 v = src[q];
        int row = q / 12, slot = q % 12;
        *(uint4*)&As[row][slot * 8] = v;
      }
    } else {
      #pragma unroll
      for (int it = 0; it < 6; ++it) {
        int q = tid + it * 256;
        int row = q / 12, slot = q % 12;
        int node = nodeBase + (row >> 4);
        int b = row & 15;
        uint4 v; int ci0;
        if (slot < 4) { v = xs4[(size_t)node * 192 + b * 12 + slot]; ci0 = slot * 8; }
        else          { v = rh4[(size_t)node * 128 + b * 8 + (slot - 4)]; ci0 = 32 + (slot - 4) * 8; }
        *(uint4*)&As[row][ci0] = v;
      }
    }
    for (int q = tid; q < NT * 12; q += 256) {
      int n = q / 12, slot = q % 12;
      uint4 v = *(const uint4*)(Wt + (size_t)n * 480 + (t0 + t) * 96 + slot * 8);
      *(uint4*)&Bs[n][slot * 8] = v;
    }
    __syncthreads();

    #pragma unroll
    for (int k32 = 0; k32 < 3; ++k32) {
      int kb = k32 * 32 + quad * 8;
      short8 a0 = *(const short8*)&As[wm + lm][kb];
      short8 a1 = *(const short8*)&As[wm + 16 + lm][kb];
      #pragma unroll
      for (int j = 0; j < NJ; ++j) {
        short8 bf = *(const short8*)&Bs[j * 16 + lm][kb];
        acc[0][j] = __builtin_amdgcn_mfma_f32_16x16x32_bf16(a0, bf, acc[0][j], 0, 0, 0);
        acc[1][j] = __builtin_amdgcn_mfma_f32_16x16x32_bf16(a1, bf, acc[1][j], 0, 0, 0);
      }
    }
    __syncthreads();
  }

  #pragma unroll
  for (int i = 0; i < 2; ++i) {
    #pragma unroll
    for (int j = 0; j < NJ; ++j) {
      int col = j * 16 + lm;
      #pragma unroll
      for (int r = 0; r < 4; ++r) {
        int row = m0 + wm + i * 16 + quad * 4 + r;
        int node = row >> 4, b = row & 15;
        float v = acc[i][j][r];
        if (MODE == 0) {
          float s = 1.f / (1.f + expf(-(bias[col] + v)));
          if (col < COUTn) {
            float hv = hglob[((size_t)b * Nn + node) * COUTn + col];
            rh0_s[(size_t)row * 64 + col] = (unsigned short)f2bfbits(s * hv);
          } else {
            U_out[(size_t)row * 64 + (col - COUTn)] = (unsigned short)f2bfbits(s);
          }
        } else if (MODE == 1) {
          outp[((size_t)b * Nn + node) * COUTn + col] = bias[col] + v;
        } else {
          size_t oa = ((size_t)b * Nn + node) * COUTn + col;
          float cp = outp[oa] + v;
          float c = tanhf(tanhf(cp));
          float u = bf2f(U_in[(size_t)row * 64 + col]);
          outp[oa] = u * hglob[oa] + (1.f - u) * c;
        }
      }
    }
  }
}

// ---------------- host ----------------
extern "C" void kernel_launch(void* const* d_in, const int* in_sizes, int n_in,
                              void* d_out, int out_size, void* d_ws, size_t ws_size,
                              hipStream_t stream) {
  const float* x   = (const float*)d_in[0];
  const float* h   = (const float*)d_in[1];
  const int*   idx = (const int*)d_in[2];
  const float* ew  = (const float*)d_in[3];
  const float* ru_param = (const float*)d_in[4];
  const float* ru_bias  = (const float*)d_in[5];
  const float* c_param  = (const float*)d_in[6];
  const float* c_bias   = (const float*)d_in[7];
  float* outp = (float*)d_out;
  (void)in_sizes; (void)n_in; (void)out_size; (void)ws_size;

  char* ws = (char*)d_ws;
  size_t off = 0;
  auto alloc = [&](size_t bytes) -> char* {
    char* p = ws + off;
    off += (bytes + 255) & ~(size_t)255;
    return p;
  };

  float* deg_f = (float*)alloc(40960);
  float* deg_b = (float*)alloc(40960);
  int*   cnt_f = (int*)alloc(40960);
  int*   cnt_b = (int*)alloc(40960);
  int*   rp_f  = (int*)alloc((Nn + 1) * sizeof(int));
  int*   rp_b  = (int*)alloc((Nn + 1) * sizeof(int));
  int*   cur_f = (int*)alloc(Nn * sizeof(int));
  int*   cur_b = (int*)alloc(Nn * sizeof(int));
  int*   flag  = (int*)alloc(256);
  unsigned int* ecf = (unsigned int*)alloc(En * sizeof(unsigned int));
  unsigned int* ecb = (unsigned int*)alloc(En * sizeof(unsigned int));
  unsigned short* Wt1 = (unsigned short*)alloc(128 * 480 * 2);
  unsigned short* Wt2 = (unsigned short*)alloc(64 * 480 * 2);

  unsigned int* A0   = (unsigned int*)alloc((size_t)Nn * WROWU * 4);
  unsigned int* T1f  = (unsigned int*)alloc((size_t)Nn * WROWU * 4);
  unsigned int* T1b  = (unsigned int*)alloc((size_t)Nn * WROWU * 4);
  unsigned int* T2f  = (unsigned int*)alloc((size_t)Nn * WROWU * 4);
  unsigned int* T2b  = (unsigned int*)alloc((size_t)Nn * WROWU * 4);
  unsigned int* rh0  = (unsigned int*)alloc((size_t)Nn * RHU * 4);
  unsigned int* rh1f = (unsigned int*)alloc((size_t)Nn * RHU * 4);
  unsigned int* rh1b = (unsigned int*)alloc((size_t)Nn * RHU * 4);
  unsigned int* Ubuf = (unsigned int*)alloc((size_t)Nn * RHU * 4);
  // ~239 MB total

  hipMemsetAsync(ws, 0, 4 * 40960, stream);
  detect_idx<<<1, 64, 0, stream>>>(idx, flag);
  deg_cnt_kernel<<<En / 256, 256, 0, stream>>>(idx, ew, deg_f, deg_b, cnt_f, cnt_b, flag);
  exscan_two<<<2, 256, 0, stream>>>(cnt_f, cnt_b, rp_f, rp_b, cur_f, cur_b, Nn);
  fill_csr<<<En / 256, 256, 0, stream>>>(idx, ew, deg_f, deg_b, cur_f, cur_b,
                                         ecf, ecb, flag);
  build_wt<<<240, 256, 0, stream>>>(ru_param, c_param, Wt1, Wt2);

  const int gBuild = Nn * WROWU / 256;

  // ===== conv1 diffusion (wide rows: 16 chunks x 48 uints) =====
  build_x0_ru<<<gBuild, 256, 0, stream>>>(x, h, A0);
  prop8_dual<48, 16><<<Nn * 16, 256, 0, stream>>>(A0, T1f, T1b, rp_f, ecf, rp_b, ecb, WROWU);
  prop8_single<48, 16><<<Nn * 16, 256, 0, stream>>>(T1f, T2f, rp_f, ecf, 2.f, WROWU);
  prop8_single<48, 16><<<Nn * 16, 256, 0, stream>>>(T1b, T2b, rp_b, ecb, 2.f, WROWU);

  // ===== conv1 projection: one MFMA GEMM K=480, fused sigmoid + r*h + u-store =====
  Msrc g1;
  g1.xs[0] = (const uint4*)A0;  g1.rh[0] = nullptr;
  g1.xs[1] = (const uint4*)T1f; g1.rh[1] = nullptr;
  g1.xs[2] = (const uint4*)T1b; g1.rh[2] = nullptr;
  g1.xs[3] = (const uint4*)T2f; g1.rh[3] = nullptr;
  g1.xs[4] = (const uint4*)T2b; g1.rh[4] = nullptr;
  gemm_mfma<128, 0><<<MROWS / 128, 256, 0, stream>>>(
      g1, 5, 0, Wt1, ru_bias, nullptr,
      (unsigned short*)rh0, (unsigned short*)Ubuf, nullptr, h);

  // ===== conv2 diffusion on rh (8 chunks x 64 uints) =====
  prop8_dual<64, 8><<<Nn * 8, 256, 0, stream>>>(rh0, rh1f, rh1b, rp_f, ecf, rp_b, ecb, RHU);

  // conv2 pass A: terms 0,1,2 (weight base t0=0)
  Msrc g2a;
  g2a.xs[0] = (const uint4*)A0;  g2a.rh[0] = (const uint4*)rh0;
  g2a.xs[1] = (const uint4*)T1f; g2a.rh[1] = (const uint4*)rh1f;
  g2a.xs[2] = (const uint4*)T1b; g2a.rh[2] = (const uint4*)rh1b;
  g2a.xs[3] = nullptr; g2a.rh[3] = nullptr;
  g2a.xs[4] = nullptr; g2a.rh[4] = nullptr;
  gemm_mfma<64, 1><<<MROWS / 128, 256, 0, stream>>>(
      g2a, 3, 0, Wt2, c_bias, outp, nullptr, nullptr, nullptr, nullptr);

  // rh second-order terms (reuse rh0/rh1f storage after pass A consumed them)
  prop8_single<64, 8><<<Nn * 8, 256, 0, stream>>>(rh1f, rh0, rp_f, ecf, 2.f, RHU);   // rh2f
  prop8_single<64, 8><<<Nn * 8, 256, 0, stream>>>(rh1b, rh1f, rp_b, ecb, 2.f, RHU);  // rh2b

  // conv2 pass B: terms 3,4 (weight base t0=3) + fused GRU final
  Msrc g2b;
  g2b.xs[0] = (const uint4*)T2f; g2b.rh[0] = (const uint4*)rh0;
  g2b.xs[1] = (const uint4*)T2b; g2b.rh[1] = (const uint4*)rh1f;
  g2b.xs[2] = nullptr; g2b.rh[2] = nullptr;
  g2b.xs[3] = nullptr; g2b.rh[3] = nullptr;
  g2b.xs[4] = nullptr; g2b.rh[4] = nullptr;
  gemm_mfma<64, 2><<<MROWS / 128, 256, 0, stream>>>(
      g2b, 2, 3, Wt2, c_bias, outp, nullptr, nullptr,
      (const unsigned short*)Ubuf, h);
}

// Round 8
// 1205.786 us; speedup vs baseline: 1.3158x; 1.3158x over previous
//
#include <hip/hip_runtime.h>
#include <stdint.h>
#include <stddef.h>

#define Bn    16
#define Nn    10000
#define En    320000
#define CIN   32
#define COUTn 64
#define CCn   96
#define WROWU 768           // uints per full node row (16 batches * 96ch / 2)
#define RHU   512           // uints per rh-only node row (16 * 64 / 2)
#define MROWS 160000        // Nn * Bn

typedef __attribute__((ext_vector_type(8))) short short8;   // 8 bf16 = 4 VGPRs
typedef __attribute__((ext_vector_type(4))) float f32x4;

// ---------------- bf16 helpers ----------------
__device__ __forceinline__ float bflo(unsigned int p) { return __uint_as_float(p << 16); }
__device__ __forceinline__ float bfhi(unsigned int p) { return __uint_as_float(p & 0xffff0000u); }
__device__ __forceinline__ float bf2f(unsigned short u) { return __uint_as_float(((unsigned int)u) << 16); }
__device__ __forceinline__ unsigned int f2bfbits(float f) {
  unsigned int x = __float_as_uint(f);
  return (x + 0x7fffu + ((x >> 16) & 1u)) >> 16;
}
__device__ __forceinline__ unsigned int pack2(float lo, float hi) {
  return f2bfbits(lo) | (f2bfbits(hi) << 16);
}

// ---------------- edge_index dtype detection ----------------
__global__ void detect_idx(const int* __restrict__ idx, int* __restrict__ flag) {
  if (threadIdx.x == 0 && blockIdx.x == 0) {
    int is64 = 1;
    for (int i = 1; i < 128; i += 2) {
      if (idx[i] != 0) { is64 = 0; break; }
    }
    flag[0] = is64;
  }
}

__device__ __forceinline__ int gidx(const int* __restrict__ p, int i, int is64) {
  return is64 ? p[2 * (long long)i] : p[i];
}

// ---------------- degree + CSR row counts ----------------
__global__ void deg_cnt_kernel(const int* __restrict__ idx, const float* __restrict__ w,
                               float* __restrict__ deg_f, float* __restrict__ deg_b,
                               int* __restrict__ cnt_f, int* __restrict__ cnt_b,
                               const int* __restrict__ flag) {
  int e = blockIdx.x * 256 + threadIdx.x;
  int is64 = flag[0];
  if (e < En) {
    int s = gidx(idx, e, is64);
    int d = gidx(idx, En + e, is64);
    float we = w[e];
    atomicAdd(&deg_f[s], we);
    atomicAdd(&deg_b[d], we);
    atomicAdd(&cnt_f[d], 1);
    atomicAdd(&cnt_b[s], 1);
  }
}

// ---------------- exclusive scan ----------------
__global__ void exscan_two(const int* __restrict__ cnt_f, const int* __restrict__ cnt_b,
                           int* __restrict__ rp_f, int* __restrict__ rp_b,
                           int* __restrict__ cur_f, int* __restrict__ cur_b, int n) {
  const int* cnt = (blockIdx.x == 0) ? cnt_f : cnt_b;
  int* rp  = (blockIdx.x == 0) ? rp_f  : rp_b;
  int* cur = (blockIdx.x == 0) ? cur_f : cur_b;
  __shared__ int sh[256];
  int t = threadIdx.x;
  int running = 0;
  for (int base = 0; base < n; base += 256) {
    int v = (base + t < n) ? cnt[base + t] : 0;
    sh[t] = v;
    __syncthreads();
    for (int off = 1; off < 256; off <<= 1) {
      int x = (t >= off) ? sh[t - off] : 0;
      __syncthreads();
      sh[t] += x;
      __syncthreads();
    }
    int excl = sh[t] - v;
    if (base + t < n) { rp[base + t] = running + excl; cur[base + t] = running + excl; }
    int total = sh[255];
    __syncthreads();
    running += total;
  }
  if (t == 0) rp[n] = running;
}

// ---------------- CSR fill (compressed edges: col<<16 | bf16 weight) ----------------
__global__ void fill_csr(const int* __restrict__ idx, const float* __restrict__ w,
                         const float* __restrict__ deg_f, const float* __restrict__ deg_b,
                         int* __restrict__ cur_f, int* __restrict__ cur_b,
                         unsigned int* __restrict__ ecf, unsigned int* __restrict__ ecb,
                         const int* __restrict__ flag) {
  int e = blockIdx.x * 256 + threadIdx.x;
  int is64 = flag[0];
  if (e < En) {
    int s = gidx(idx, e, is64);
    int d = gidx(idx, En + e, is64);
    float we = w[e];
    int pf = atomicAdd(&cur_f[d], 1);   // forward rows=dst, col=src, w=we/deg_f[src]
    ecf[pf] = ((unsigned int)s << 16) | f2bfbits(we / deg_f[s]);
    int pb = atomicAdd(&cur_b[s], 1);   // backward rows=src, col=dst, w=we/deg_b[dst]
    ecb[pb] = ((unsigned int)d << 16) | f2bfbits(we / deg_b[d]);
  }
}

// ---------------- weight prep: transposed bf16, W0 folded (W0-W3-W4) ----------------
__global__ void build_wt(const float* __restrict__ ru_p, const float* __restrict__ c_p,
                         unsigned short* __restrict__ Wt1, unsigned short* __restrict__ Wt2) {
  int i = blockIdx.x * 256 + threadIdx.x;
  if (i < 128 * 480) {
    int n = i / 480, k = i % 480;
    int t = k / 96, kk = k % 96;
    float v;
    if (t == 0) v = ru_p[(kk * 5 + 0) * 128 + n] - ru_p[(kk * 5 + 3) * 128 + n] - ru_p[(kk * 5 + 4) * 128 + n];
    else        v = ru_p[(kk * 5 + t) * 128 + n];
    Wt1[i] = (unsigned short)f2bfbits(v);
  }
  if (i < 64 * 480) {
    int n = i / 480, k = i % 480;
    int t = k / 96, kk = k % 96;
    float v;
    if (t == 0) v = c_p[(kk * 5 + 0) * 64 + n] - c_p[(kk * 5 + 3) * 64 + n] - c_p[(kk * 5 + 4) * 64 + n];
    else        v = c_p[(kk * 5 + t) * 64 + n];
    Wt2[i] = (unsigned short)f2bfbits(v);
  }
}

// ---------------- X0 builder ----------------
__global__ void build_x0_ru(const float* __restrict__ x, const float* __restrict__ h,
                            unsigned int* __restrict__ X0) {
  long long p = (long long)blockIdx.x * 256 + threadIdx.x;
  int node = (int)(p / WROWU);
  int rem = (int)(p % WROWU);
  int b = rem / 48;
  int ci = (rem % 48) * 2;
  float lo, hi;
  if (ci < CIN) {
    const float* s = x + ((size_t)b * Nn + node) * CIN + ci;
    lo = s[0]; hi = s[1];
  } else {
    const float* s = h + ((size_t)b * Nn + node) * COUTn + (ci - CIN);
    lo = s[0]; hi = s[1];
  }
  X0[p] = pack2(lo, hi);
}

// ---------------- XCD-pinned propagate, round-3 inner loop, single-wave blocks ----------------
// Grid idx = row*NCHUNK + c (NCHUNK%8==0) -> chunk c on XCD c%8 (round-robin dispatch).
// Per-XCD resident input slice: Nn*CSZ*4*(NCHUNK/8) bytes (3.84 MB wide / 2.56 MB rh).
// Edges + outputs use nontemporal hints so only the input slice occupies L2.
// Lane owns one uint of the chunk; serial edge loop, 4 gathers in flight.
template<int CSZ>
__device__ __forceinline__ void propL2_body(const unsigned int* __restrict__ in,
                                            unsigned int* __restrict__ out,
                                            const int* __restrict__ rowptr,
                                            const unsigned int* __restrict__ ec,
                                            float alpha, int rowU, int row, int coff,
                                            unsigned int* sec) {
  int lane = threadIdx.x;
  int uoff = coff + lane;
  float alo = 0.f, ahi = 0.f;
  int jb = rowptr[row], je = rowptr[row + 1];
  for (int base = jb; base < je; base += 64) {
    int m = je - base; if (m > 64) m = 64;
    __syncthreads();
    if (lane < m) sec[lane] = __builtin_nontemporal_load(&ec[base + lane]);
    __syncthreads();
    if (lane < CSZ) {
      int j = 0;
      for (; j + 4 <= m; j += 4) {
        unsigned int e0 = sec[j + 0], e1 = sec[j + 1], e2 = sec[j + 2], e3 = sec[j + 3];
        unsigned int p0 = in[(size_t)(e0 >> 16) * rowU + uoff];
        unsigned int p1 = in[(size_t)(e1 >> 16) * rowU + uoff];
        unsigned int p2 = in[(size_t)(e2 >> 16) * rowU + uoff];
        unsigned int p3 = in[(size_t)(e3 >> 16) * rowU + uoff];
        float w0 = bflo(e0), w1 = bflo(e1), w2 = bflo(e2), w3 = bflo(e3);
        alo += w0 * bflo(p0); ahi += w0 * bfhi(p0);
        alo += w1 * bflo(p1); ahi += w1 * bfhi(p1);
        alo += w2 * bflo(p2); ahi += w2 * bfhi(p2);
        alo += w3 * bflo(p3); ahi += w3 * bfhi(p3);
      }
      for (; j < m; ++j) {
        unsigned int e0 = sec[j];
        unsigned int p0 = in[(size_t)(e0 >> 16) * rowU + uoff];
        float w0 = bflo(e0);
        alo += w0 * bflo(p0); ahi += w0 * bfhi(p0);
      }
    }
  }
  if (lane < CSZ)
    __builtin_nontemporal_store(pack2(alpha * alo, alpha * ahi),
                                &out[(size_t)row * rowU + uoff]);
}

template<int CSZ, int NCHUNK>
__launch_bounds__(64)
__global__ void propL2_single(const unsigned int* __restrict__ in, unsigned int* __restrict__ out,
                              const int* __restrict__ rowptr, const unsigned int* __restrict__ ec,
                              float alpha, int rowU) {
  __shared__ unsigned int sec[64];
  int row = blockIdx.x / NCHUNK;
  int c = blockIdx.x % NCHUNK;
  propL2_body<CSZ>(in, out, rowptr, ec, alpha, rowU, row, c * CSZ, sec);
}

template<int CSZ, int NCHUNK>
__launch_bounds__(64)
__global__ void propL2_dual(const unsigned int* __restrict__ in,
                            unsigned int* __restrict__ outF, unsigned int* __restrict__ outB,
                            const int* __restrict__ rp_f, const unsigned int* __restrict__ ecf,
                            const int* __restrict__ rp_b, const unsigned int* __restrict__ ecb,
                            int rowU) {
  __shared__ unsigned int sec[64];
  int row = blockIdx.x / NCHUNK;
  int c = blockIdx.x % NCHUNK;
  int coff = c * CSZ;
  propL2_body<CSZ>(in, outF, rp_f, ecf, 1.f, rowU, row, coff, sec);
  __syncthreads();
  propL2_body<CSZ>(in, outB, rp_b, ecb, 1.f, rowU, row, coff, sec);
}

// ---------------- MFMA multi-term GEMM ----------------
// C[128 x NT] per block; 4 waves, each 32 x NT. K = nterms*96.
// Weight columns for loop term t: (t0 + t)*96.
// MODE 0: conv1 epilogue: v=sigmoid(bias+acc); col<64 -> rh0=v*h (bf16); else U=v (bf16)
// MODE 1: outp = bias + acc (f32, batch-major)
// MODE 2: cp = outp + acc; c=tanh(tanh(cp)); u from U_in; outp = u*h + (1-u)*c
struct Msrc {
  const uint4* xs[5];
  const uint4* rh[5];
};

template<int NT, int MODE>
__launch_bounds__(256)
__global__ void gemm_mfma(Msrc g, int nterms, int t0,
                          const unsigned short* __restrict__ Wt,
                          const float* __restrict__ bias,
                          float* __restrict__ outp,
                          unsigned short* __restrict__ rh0_s,
                          unsigned short* __restrict__ U_out,
                          const unsigned short* __restrict__ U_in,
                          const float* __restrict__ hglob) {
  constexpr int NJ = NT / 16;
  __shared__ __align__(16) unsigned short As[128][104];   // 13 x 16B per row (odd -> conflict-free)
  __shared__ __align__(16) unsigned short Bs[NT][104];

  int m0 = blockIdx.x * 128;
  int tid = threadIdx.x;
  int wave = tid >> 6;
  int lane = tid & 63;
  int quad = lane >> 4;
  int lm = lane & 15;
  int wm = wave * 32;
  int nodeBase = m0 >> 4;

  f32x4 acc[2][NJ];
  #pragma unroll
  for (int i = 0; i < 2; ++i)
    #pragma unroll
    for (int j = 0; j < NJ; ++j) acc[i][j] = (f32x4){0.f, 0.f, 0.f, 0.f};

  for (int t = 0; t < nterms; ++t) {
    const uint4* xs4 = g.xs[t];
    const uint4* rh4 = g.rh[t];
    if (rh4 == nullptr) {
      const uint4* src = xs4 + (size_t)m0 * 12;
      #pragma unroll
      for (int it = 0; it < 6; ++it) {
        int q = tid + it * 256;
        uint4 v = src[q];
        int row = q / 12, slot = q % 12;
        *(uint4*)&As[row][slot * 8] = v;
      }
    } else {
      #pragma unroll
      for (int it = 0; it < 6; ++it) {
        int q = tid + it * 256;
        int row = q / 12, slot = q % 12;
        int node = nodeBase + (row >> 4);
        int b = row & 15;
        uint4 v; int ci0;
        if (slot < 4) { v = xs4[(size_t)node * 192 + b * 12 + slot]; ci0 = slot * 8; }
        else          { v = rh4[(size_t)node * 128 + b * 8 + (slot - 4)]; ci0 = 32 + (slot - 4) * 8; }
        *(uint4*)&As[row][ci0] = v;
      }
    }
    for (int q = tid; q < NT * 12; q += 256) {
      int n = q / 12, slot = q % 12;
      uint4 v = *(const uint4*)(Wt + (size_t)n * 480 + (t0 + t) * 96 + slot * 8);
      *(uint4*)&Bs[n][slot * 8] = v;
    }
    __syncthreads();

    #pragma unroll
    for (int k32 = 0; k32 < 3; ++k32) {
      int kb = k32 * 32 + quad * 8;
      short8 a0 = *(const short8*)&As[wm + lm][kb];
      short8 a1 = *(const short8*)&As[wm + 16 + lm][kb];
      #pragma unroll
      for (int j = 0; j < NJ; ++j) {
        short8 bf = *(const short8*)&Bs[j * 16 + lm][kb];
        acc[0][j] = __builtin_amdgcn_mfma_f32_16x16x32_bf16(a0, bf, acc[0][j], 0, 0, 0);
        acc[1][j] = __builtin_amdgcn_mfma_f32_16x16x32_bf16(a1, bf, acc[1][j], 0, 0, 0);
      }
    }
    __syncthreads();
  }

  #pragma unroll
  for (int i = 0; i < 2; ++i) {
    #pragma unroll
    for (int j = 0; j < NJ; ++j) {
      int col = j * 16 + lm;
      #pragma unroll
      for (int r = 0; r < 4; ++r) {
        int row = m0 + wm + i * 16 + quad * 4 + r;
        int node = row >> 4, b = row & 15;
        float v = acc[i][j][r];
        if (MODE == 0) {
          float s = 1.f / (1.f + expf(-(bias[col] + v)));
          if (col < COUTn) {
            float hv = hglob[((size_t)b * Nn + node) * COUTn + col];
            rh0_s[(size_t)row * 64 + col] = (unsigned short)f2bfbits(s * hv);
          } else {
            U_out[(size_t)row * 64 + (col - COUTn)] = (unsigned short)f2bfbits(s);
          }
        } else if (MODE == 1) {
          outp[((size_t)b * Nn + node) * COUTn + col] = bias[col] + v;
        } else {
          size_t oa = ((size_t)b * Nn + node) * COUTn + col;
          float cp = outp[oa] + v;
          float c = tanhf(tanhf(cp));
          float u = bf2f(U_in[(size_t)row * 64 + col]);
          outp[oa] = u * hglob[oa] + (1.f - u) * c;
        }
      }
    }
  }
}

// ---------------- host ----------------
extern "C" void kernel_launch(void* const* d_in, const int* in_sizes, int n_in,
                              void* d_out, int out_size, void* d_ws, size_t ws_size,
                              hipStream_t stream) {
  const float* x   = (const float*)d_in[0];
  const float* h   = (const float*)d_in[1];
  const int*   idx = (const int*)d_in[2];
  const float* ew  = (const float*)d_in[3];
  const float* ru_param = (const float*)d_in[4];
  const float* ru_bias  = (const float*)d_in[5];
  const float* c_param  = (const float*)d_in[6];
  const float* c_bias   = (const float*)d_in[7];
  float* outp = (float*)d_out;
  (void)in_sizes; (void)n_in; (void)out_size; (void)ws_size;

  char* ws = (char*)d_ws;
  size_t off = 0;
  auto alloc = [&](size_t bytes) -> char* {
    char* p = ws + off;
    off += (bytes + 255) & ~(size_t)255;
    return p;
  };

  float* deg_f = (float*)alloc(40960);
  float* deg_b = (float*)alloc(40960);
  int*   cnt_f = (int*)alloc(40960);
  int*   cnt_b = (int*)alloc(40960);
  int*   rp_f  = (int*)alloc((Nn + 1) * sizeof(int));
  int*   rp_b  = (int*)alloc((Nn + 1) * sizeof(int));
  int*   cur_f = (int*)alloc(Nn * sizeof(int));
  int*   cur_b = (int*)alloc(Nn * sizeof(int));
  int*   flag  = (int*)alloc(256);
  unsigned int* ecf = (unsigned int*)alloc(En * sizeof(unsigned int));
  unsigned int* ecb = (unsigned int*)alloc(En * sizeof(unsigned int));
  unsigned short* Wt1 = (unsigned short*)alloc(128 * 480 * 2);
  unsigned short* Wt2 = (unsigned short*)alloc(64 * 480 * 2);

  unsigned int* A0   = (unsigned int*)alloc((size_t)Nn * WROWU * 4);
  unsigned int* T1f  = (unsigned int*)alloc((size_t)Nn * WROWU * 4);
  unsigned int* T1b  = (unsigned int*)alloc((size_t)Nn * WROWU * 4);
  unsigned int* T2f  = (unsigned int*)alloc((size_t)Nn * WROWU * 4);
  unsigned int* T2b  = (unsigned int*)alloc((size_t)Nn * WROWU * 4);
  unsigned int* rh0  = (unsigned int*)alloc((size_t)Nn * RHU * 4);
  unsigned int* rh1f = (unsigned int*)alloc((size_t)Nn * RHU * 4);
  unsigned int* rh1b = (unsigned int*)alloc((size_t)Nn * RHU * 4);
  unsigned int* Ubuf = (unsigned int*)alloc((size_t)Nn * RHU * 4);
  // ~239 MB total

  hipMemsetAsync(ws, 0, 4 * 40960, stream);
  detect_idx<<<1, 64, 0, stream>>>(idx, flag);
  deg_cnt_kernel<<<En / 256, 256, 0, stream>>>(idx, ew, deg_f, deg_b, cnt_f, cnt_b, flag);
  exscan_two<<<2, 256, 0, stream>>>(cnt_f, cnt_b, rp_f, rp_b, cur_f, cur_b, Nn);
  fill_csr<<<En / 256, 256, 0, stream>>>(idx, ew, deg_f, deg_b, cur_f, cur_b,
                                         ecf, ecb, flag);
  build_wt<<<240, 256, 0, stream>>>(ru_param, c_param, Wt1, Wt2);

  const int gBuild = Nn * WROWU / 256;

  // ===== conv1 diffusion (wide rows: 16 chunks x 48 uints) =====
  build_x0_ru<<<gBuild, 256, 0, stream>>>(x, h, A0);
  propL2_dual<48, 16><<<Nn * 16, 64, 0, stream>>>(A0, T1f, T1b, rp_f, ecf, rp_b, ecb, WROWU);
  propL2_single<48, 16><<<Nn * 16, 64, 0, stream>>>(T1f, T2f, rp_f, ecf, 2.f, WROWU);
  propL2_single<48, 16><<<Nn * 16, 64, 0, stream>>>(T1b, T2b, rp_b, ecb, 2.f, WROWU);

  // ===== conv1 projection: one MFMA GEMM K=480, fused sigmoid + r*h + u-store =====
  Msrc g1;
  g1.xs[0] = (const uint4*)A0;  g1.rh[0] = nullptr;
  g1.xs[1] = (const uint4*)T1f; g1.rh[1] = nullptr;
  g1.xs[2] = (const uint4*)T1b; g1.rh[2] = nullptr;
  g1.xs[3] = (const uint4*)T2f; g1.rh[3] = nullptr;
  g1.xs[4] = (const uint4*)T2b; g1.rh[4] = nullptr;
  gemm_mfma<128, 0><<<MROWS / 128, 256, 0, stream>>>(
      g1, 5, 0, Wt1, ru_bias, nullptr,
      (unsigned short*)rh0, (unsigned short*)Ubuf, nullptr, h);

  // ===== conv2 diffusion on rh (8 chunks x 64 uints) =====
  propL2_dual<64, 8><<<Nn * 8, 64, 0, stream>>>(rh0, rh1f, rh1b, rp_f, ecf, rp_b, ecb, RHU);

  // conv2 pass A: terms 0,1,2 (weight base t0=0)
  Msrc g2a;
  g2a.xs[0] = (const uint4*)A0;  g2a.rh[0] = (const uint4*)rh0;
  g2a.xs[1] = (const uint4*)T1f; g2a.rh[1] = (const uint4*)rh1f;
  g2a.xs[2] = (const uint4*)T1b; g2a.rh[2] = (const uint4*)rh1b;
  g2a.xs[3] = nullptr; g2a.rh[3] = nullptr;
  g2a.xs[4] = nullptr; g2a.rh[4] = nullptr;
  gemm_mfma<64, 1><<<MROWS / 128, 256, 0, stream>>>(
      g2a, 3, 0, Wt2, c_bias, outp, nullptr, nullptr, nullptr, nullptr);

  // rh second-order terms (reuse rh0/rh1f storage after pass A consumed them)
  propL2_single<64, 8><<<Nn * 8, 64, 0, stream>>>(rh1f, rh0, rp_f, ecf, 2.f, RHU);   // rh2f
  propL2_single<64, 8><<<Nn * 8, 64, 0, stream>>>(rh1b, rh1f, rp_b, ecb, 2.f, RHU);  // rh2b

  // conv2 pass B: terms 3,4 (weight base t0=3) + fused GRU final
  Msrc g2b;
  g2b.xs[0] = (const uint4*)T2f; g2b.rh[0] = (const uint4*)rh0;
  g2b.xs[1] = (const uint4*)T2b; g2b.rh[1] = (const uint4*)rh1f;
  g2b.xs[2] = nullptr; g2b.rh[2] = nullptr;
  g2b.xs[3] = nullptr; g2b.rh[3] = nullptr;
  g2b.xs[4] = nullptr; g2b.rh[4] = nullptr;
  gemm_mfma<64, 2><<<MROWS / 128, 256, 0, stream>>>(
      g2b, 2, 3, Wt2, c_bias, outp, nullptr, nullptr,
      (const unsigned short*)Ubuf, h);
}